// Round 11
// baseline (164.737 us; speedup 1.0000x reference)
//
#include <hip/hip_runtime.h>
#include <math.h>

#define GRIDC  48
#define CELLS  (GRIDC*GRIDC*GRIDC)   // 110592
#define NBLK1  (CELLS/1024)          // 108 scan1 blocks
#define EXT    96.0f                 // grid covers [-96,96]^3 (4.8 sigma)
#define CSZ    4.0f
#define INVC   0.25f
#define STOP_MARGIN 0.1f             // >> max |computed sq - math sq| (~0.04)

// ---------- rounding-exact helpers (match numpy exactly) ----------
__device__ __forceinline__ float mul_rn(float a, float b) {
#pragma clang fp contract(off)
    return a * b;
}
__device__ __forceinline__ float add_rn(float a, float b) {
#pragma clang fp contract(off)
    return a + b;
}
__device__ __forceinline__ float sumsq3(float x, float y, float z) {
    return add_rn(add_rn(mul_rn(x, x), mul_rn(y, y)), mul_rn(z, z));
}
__device__ __forceinline__ float med3f(float a, float b, float c) {
    return __builtin_amdgcn_fmed3f(a, b, c);
}
// EXACT sq = (||a||^2 + ||b||^2) - 2*dot — bit-matches the reference.
__device__ __forceinline__ float pair_sq(float a0, float a1, float a2, float an,
                                         float bx, float by, float bz, float bw) {
    const float dot = __builtin_fmaf(a2, bz,
                      __builtin_fmaf(a1, by, mul_rn(a0, bx)));
    return __builtin_fmaf(-2.0f, dot, add_rn(an, bw));
}
// top-3 values (in-place write order needs no temps)
__device__ __forceinline__ void val3_push(float& d0, float& d1, float& d2, float v) {
    d2 = med3f(d1, d2, v);
    d1 = med3f(d0, d1, v);
    d0 = fminf(d0, v);
}
// lexicographic (sq, idx) top-3 insert — order-independent, == lax.top_k
__device__ __forceinline__ void lex3_push(float& d0, float& d1, float& d2,
                                          int& i0, int& i1, int& i2,
                                          float sq, int idx) {
    const bool l0 = (sq < d0) || (sq == d0 && idx < i0);
    const bool l1 = (sq < d1) || (sq == d1 && idx < i1);
    const bool l2 = (sq < d2) || (sq == d2 && idx < i2);
    i2 = l1 ? i1 : (l2 ? idx : i2);
    d2 = l1 ? d1 : (l2 ? sq  : d2);
    i1 = l0 ? i0 : (l1 ? idx : i1);
    d1 = l0 ? d0 : (l1 ? sq  : d1);
    i0 = l0 ? idx : i0;
    d0 = l0 ? sq  : d0;
}
__device__ __forceinline__ void cell_coords(float x, float y, float z,
                                            int& cx, int& cy, int& cz) {
    cx = min(max((int)floorf((x + EXT) * INVC), 0), GRIDC - 1);
    cy = min(max((int)floorf((y + EXT) * INVC), 0), GRIDC - 1);
    cz = min(max((int)floorf((z + EXT) * INVC), 0), GRIDC - 1);
}
// exact small-int division via 2^40 magic (d < 65536, x*err < 2^40)
__device__ __forceinline__ int qdiv(int x, unsigned long long magic) {
    return (int)(((unsigned long long)(unsigned)x * magic) >> 40);
}

// ---------- binning ----------
__global__ __launch_bounds__(256) void zero_kernel(int* __restrict__ a) {
    a[blockIdx.x * 256 + threadIdx.x] = 0;
}

__global__ __launch_bounds__(256) void count_kernel(
    const float* __restrict__ r, int* __restrict__ counts, int M)
{
    const int i = blockIdx.x * 256 + threadIdx.x;
    if (i < M) {
        int cx, cy, cz;
        cell_coords(r[3 * i], r[3 * i + 1], r[3 * i + 2], cx, cy, cz);
        atomicAdd(&counts[(cz * GRIDC + cy) * GRIDC + cx], 1);
    }
}

// scan1: per-block (1024 cells) exclusive scan + block total
__global__ __launch_bounds__(256) void scan1_kernel(
    const int* __restrict__ counts, int* __restrict__ cellLoc,
    int* __restrict__ bsum)
{
    __shared__ int arr[256];
    const int tid = threadIdx.x;
    const int base = blockIdx.x * 1024 + tid * 4;
    const int4 c = *(const int4*)(counts + base);
    const int t1 = c.x, t2 = c.x + c.y, t3 = t2 + c.z, tot = t3 + c.w;
    arr[tid] = tot;
    __syncthreads();
    for (int off = 1; off < 256; off <<= 1) {
        const int w = (tid >= off) ? arr[tid - off] : 0;
        __syncthreads();
        arr[tid] += w;
        __syncthreads();
    }
    const int excl = arr[tid] - tot;
    *(int4*)(cellLoc + base) = make_int4(excl, excl + t1, excl + t2, excl + t3);
    if (tid == 255) bsum[blockIdx.x] = arr[255];
}

// scan2: exclusive scan of the NBLK1 block sums (single block, 128 thr)
__global__ __launch_bounds__(128) void scan2_kernel(
    const int* __restrict__ bsum, int* __restrict__ bscan)
{
    __shared__ int arr[128];
    const int tid = threadIdx.x;
    const int v = (tid < NBLK1) ? bsum[tid] : 0;
    arr[tid] = v;
    __syncthreads();
    for (int off = 1; off < 128; off <<= 1) {
        const int w = (tid >= off) ? arr[tid - off] : 0;
        __syncthreads();
        arr[tid] += w;
        __syncthreads();
    }
    if (tid < NBLK1) bscan[tid] = arr[tid] - v;
}

// scan3: final offsets + scatter cursors
__global__ __launch_bounds__(256) void scan3_kernel(
    const int* __restrict__ cellLoc, const int* __restrict__ bscan,
    int* __restrict__ cellStart, int* __restrict__ cellCur)
{
    const int i = blockIdx.x * 256 + threadIdx.x;
    const int v = cellLoc[i] + bscan[i >> 10];
    cellStart[i] = v;
    cellCur[i] = v;
}

__global__ __launch_bounds__(256) void scatter_kernel(
    const float* __restrict__ r, int* __restrict__ cellCur,
    float4* __restrict__ pts4, int* __restrict__ pidx, int M)
{
    const int i = blockIdx.x * 256 + threadIdx.x;
    if (i < M) {
        const float x = r[3 * i], y = r[3 * i + 1], z = r[3 * i + 2];
        int cx, cy, cz;
        cell_coords(x, y, z, cx, cy, cz);
        const int pos = atomicAdd(&cellCur[(cz * GRIDC + cy) * GRIDC + cx], 1);
        pts4[pos] = make_float4(x, y, z, sumsq3(x, y, z));  // bw exact
        pidx[pos] = i;
    }
}

// ---------- KNN: one wave per query, exact ring search ----------
// Ring t scans the Chebyshev shell of cells around the query's cell, lanes
// parallel over shell cells. Stop when g2 (3rd-smallest scanned sq, exact
// reference rounding) <= bound^2 - STOP_MARGIN, where bound is the distance
// from the query to the unscanned half-spaces (clipped at grid edges; points
// clamped into boundary cells lie beyond those faces, so the bound stays
// conservative). Candidate order is irrelevant: lex3_push tie-breaks on idx.
__global__ __launch_bounds__(256) void knn_kernel(
    const float* __restrict__ q, const float4* __restrict__ pts4,
    const int* __restrict__ pidx, const int* __restrict__ cellStart,
    const int* __restrict__ counts, const float* __restrict__ flow,
    float* __restrict__ out)
{
    const int lane = threadIdx.x & 63;
    const int qi = blockIdx.x * 4 + (threadIdx.x >> 6);

    const float a0 = q[qi * 3 + 0];
    const float a1 = q[qi * 3 + 1];
    const float a2 = q[qi * 3 + 2];
    const float an = sumsq3(a0, a1, a2);
    int cx, cy, cz;
    cell_coords(a0, a1, a2, cx, cy, cz);

    float d0 = __builtin_inff(), d1 = __builtin_inff(), d2 = __builtin_inff();
    int   i0 = 0x7fffffff, i1 = 0x7fffffff, i2 = 0x7fffffff;

    for (int t = 0; t <= 2 * GRIDC; ++t) {
        const int side = 2 * t + 1;
        const int area = side * side;
        const int vol  = area * side;
        const unsigned long long magA = ((1ull << 40) + area - 1) / (unsigned)area;
        const unsigned long long magS = ((1ull << 40) + side - 1) / (unsigned)side;

        for (int i = lane; i < vol; i += 64) {
            const int dz = qdiv(i, magA);
            const int rm = i - dz * area;
            const int dy = qdiv(rm, magS);
            const int dx = rm - dy * side;
            const int ox = dx - t, oy = dy - t, oz = dz - t;
            const int m = max(abs(ox), max(abs(oy), abs(oz)));
            if (m != t) continue;                       // shell only
            const int ux = cx + ox, uy = cy + oy, uz = cz + oz;
            if ((unsigned)ux >= GRIDC || (unsigned)uy >= GRIDC ||
                (unsigned)uz >= GRIDC) continue;        // skip (no clamping!)
            const int cell = (uz * GRIDC + uy) * GRIDC + ux;
            const int st = cellStart[cell];
            const int cn = counts[cell];
            for (int j = 0; j < cn; ++j) {
                const float4 p = pts4[st + j];
                const int idx = pidx[st + j];
                const float sq = pair_sq(a0, a1, a2, an, p.x, p.y, p.z, p.w);
                lex3_push(d0, d1, d2, i0, i1, i2, sq, idx);
            }
        }

        // wave-wide 3rd-smallest VALUE (all lanes end with same g0..g2)
        float g0 = d0, g1 = d1, g2 = d2;
#pragma unroll
        for (int m = 1; m < 64; m <<= 1) {
            const float e0 = __shfl_xor(g0, m);
            const float e1 = __shfl_xor(g1, m);
            const float e2 = __shfl_xor(g2, m);
            val3_push(g0, g1, g2, e0);
            val3_push(g0, g1, g2, e1);
            val3_push(g0, g1, g2, e2);
        }

        // distance bound to the unscanned region (6 clipped half-spaces)
        float bnd = __builtin_inff();
        const int lox = cx - t, hix = cx + t;
        const int loy = cy - t, hiy = cy + t;
        const int loz = cz - t, hiz = cz + t;
        if (lox > 0)         bnd = fminf(bnd, a0 - ((float)lox * CSZ - EXT));
        if (hix < GRIDC - 1) bnd = fminf(bnd, ((float)(hix + 1) * CSZ - EXT) - a0);
        if (loy > 0)         bnd = fminf(bnd, a1 - ((float)loy * CSZ - EXT));
        if (hiy < GRIDC - 1) bnd = fminf(bnd, ((float)(hiy + 1) * CSZ - EXT) - a1);
        if (loz > 0)         bnd = fminf(bnd, a2 - ((float)loz * CSZ - EXT));
        if (hiz < GRIDC - 1) bnd = fminf(bnd, ((float)(hiz + 1) * CSZ - EXT) - a2);

        if (__builtin_isinf(bnd)) break;                // whole grid scanned
        if (g2 <= __builtin_fmaf(bnd, bnd, -STOP_MARGIN)) break;
    }

    // lexicographic butterfly merge across the 64 lanes
#pragma unroll
    for (int m = 1; m < 64; m <<= 1) {
        const float e0 = __shfl_xor(d0, m);
        const float e1 = __shfl_xor(d1, m);
        const float e2 = __shfl_xor(d2, m);
        const int   j0 = __shfl_xor(i0, m);
        const int   j1 = __shfl_xor(i1, m);
        const int   j2 = __shfl_xor(i2, m);
        lex3_push(d0, d1, d2, i0, i1, i2, e0, j0);
        lex3_push(d0, d1, d2, i0, i1, i2, e1, j1);
        lex3_push(d0, d1, d2, i0, i1, i2, e2, j2);
    }

    // epilogue (rounding-exact, matches reference op order)
    if (lane == 0) {
        const float t0 = sqrtf(fmaxf(d0, 1e-12f));
        const float t1 = sqrtf(fmaxf(d1, 1e-12f));
        const float t2 = sqrtf(fmaxf(d2, 1e-12f));
        const float w0r = 1.0f / add_rn(t0, 1e-8f);
        const float w1r = 1.0f / add_rn(t1, 1e-8f);
        const float w2r = 1.0f / add_rn(t2, 1e-8f);
        const float wsum = add_rn(add_rn(w0r, w1r), w2r);
        const float w0 = w0r / wsum;
        const float w1 = w1r / wsum;
        const float w2 = w2r / wsum;

        const float f00 = flow[3 * i0 + 0], f01 = flow[3 * i0 + 1], f02 = flow[3 * i0 + 2];
        const float f10 = flow[3 * i1 + 0], f11 = flow[3 * i1 + 1], f12 = flow[3 * i1 + 2];
        const float f20 = flow[3 * i2 + 0], f21 = flow[3 * i2 + 1], f22 = flow[3 * i2 + 2];

        out[qi * 3 + 0] = add_rn(add_rn(mul_rn(w0, f00), mul_rn(w1, f10)), mul_rn(w2, f20));
        out[qi * 3 + 1] = add_rn(add_rn(mul_rn(w0, f01), mul_rn(w1, f11)), mul_rn(w2, f21));
        out[qi * 3 + 2] = add_rn(add_rn(mul_rn(w0, f02), mul_rn(w1, f12)), mul_rn(w2, f22));
    }
}

extern "C" void kernel_launch(void* const* d_in, const int* in_sizes, int n_in,
                              void* d_out, int out_size, void* d_ws, size_t ws_size,
                              hipStream_t stream) {
    const float* q    = (const float*)d_in[0];
    const float* r    = (const float*)d_in[1];
    const float* flow = (const float*)d_in[2];
    // d_in[3] is k (==3), hard-coded.

    const int N = in_sizes[0] / 3;
    const int M = in_sizes[1] / 3;

    // ws layout (all within ~2 MB):
    int* counts    = (int*)d_ws;                 // CELLS
    int* cellLoc   = counts + CELLS;             // CELLS
    int* bsum      = cellLoc + CELLS;            // 128 (NBLK1 used)
    int* bscan     = bsum + 128;                 // 128
    int* cellStart = bscan + 128;                // CELLS
    int* cellCur   = cellStart + CELLS;          // CELLS
    float4* pts4   = (float4*)(cellCur + CELLS); // M  (offset is 16B-aligned)
    int* pidx      = (int*)(pts4 + M);           // M
    (void)ws_size;

    const int mb = (M + 255) / 256;

    zero_kernel<<<CELLS / 256, 256, 0, stream>>>(counts);
    count_kernel<<<mb, 256, 0, stream>>>(r, counts, M);
    scan1_kernel<<<NBLK1, 256, 0, stream>>>(counts, cellLoc, bsum);
    scan2_kernel<<<1, 128, 0, stream>>>(bsum, bscan);
    scan3_kernel<<<CELLS / 256, 256, 0, stream>>>(cellLoc, bscan, cellStart, cellCur);
    scatter_kernel<<<mb, 256, 0, stream>>>(r, cellCur, pts4, pidx, M);

    knn_kernel<<<N / 4, 256, 0, stream>>>(q, pts4, pidx, cellStart, counts,
                                          flow, (float*)d_out);
}